// Round 1
// baseline (98.109 us; speedup 1.0000x reference)
//
#include <hip/hip_runtime.h>

#define G_ 8
#define C_ 64
#define K_ 9
#define H_ 100
#define W_ 160
#define PAD_ 1

__global__ __launch_bounds__(256) void dcn_kernel(
    const float* __restrict__ x,      // [H,W,G*C]
    const float* __restrict__ offset, // [H,W,G*K*2]
    const float* __restrict__ mask,   // [H,W,G*K]
    float* __restrict__ out)          // [H,W,G*C]
{
    // one wave per (pixel, group); lane = channel
    const int wave_id = (blockIdx.x * blockDim.x + threadIdx.x) >> 6;
    const int lane = threadIdx.x & 63;
    if (wave_id >= H_ * W_ * G_) return;
    const int g   = wave_id & (G_ - 1);
    const int pix = wave_id >> 3;          // G_ == 8
    const int w   = pix % W_;
    const int h   = pix / W_;

    // ---- softmax over mask[h,w,g,0..8] (wave-uniform) ----
    const float* mptr = mask + ((size_t)(h * W_ + w) * G_ + g) * K_;
    float mv[K_];
    float mmax = -1e30f;
#pragma unroll
    for (int k = 0; k < K_; ++k) {
        mv[k] = mptr[k];
        mmax = fmaxf(mmax, mv[k]);
    }
    float msum = 0.f;
#pragma unroll
    for (int k = 0; k < K_; ++k) {
        mv[k] = __expf(mv[k] - mmax);
        msum += mv[k];
    }
    const float minv = 1.f / msum;

    const float* optr = offset + ((size_t)(h * W_ + w) * G_ + g) * (K_ * 2);
    const float* xg   = x + g * C_ + lane;   // lane = channel

    float acc = 0.f;
#pragma unroll
    for (int k = 0; k < K_; ++k) {
        const int ky = k / 3 - PAD_;
        const int kx = k % 3 - PAD_;
        const float loc_h = (float)(h + ky) + optr[2 * k];
        const float loc_w = (float)(w + kx) + optr[2 * k + 1];
        const float fh0 = floorf(loc_h);
        const float fw0 = floorf(loc_w);
        const float th = loc_h - fh0;
        const float tw = loc_w - fw0;
        const int h0 = (int)fh0;
        const int w0 = (int)fw0;
        const float m = mv[k] * minv;

        float v = 0.f;
#pragma unroll
        for (int dh = 0; dh < 2; ++dh) {
#pragma unroll
            for (int dw = 0; dw < 2; ++dw) {
                const int hi = h0 + dh;
                const int wi = w0 + dw;
                const float wt = (dh ? th : (1.f - th)) * (dw ? tw : (1.f - tw));
                const bool valid = (hi >= 0) && (hi < H_) && (wi >= 0) && (wi < W_);
                const int hc = min(max(hi, 0), H_ - 1);
                const int wc = min(max(wi, 0), W_ - 1);
                const float s = xg[(size_t)(hc * W_ + wc) * (G_ * C_)];
                v += s * (valid ? wt : 0.f);
            }
        }
        acc += v * m;
    }

    out[((size_t)(h * W_ + w) * G_ + g) * C_ + lane] = acc;
}

extern "C" void kernel_launch(void* const* d_in, const int* in_sizes, int n_in,
                              void* d_out, int out_size, void* d_ws, size_t ws_size,
                              hipStream_t stream) {
    const float* x      = (const float*)d_in[0];
    const float* offset = (const float*)d_in[1];
    const float* mask   = (const float*)d_in[2];
    float* out          = (float*)d_out;

    const int total_waves   = H_ * W_ * G_;       // 128000
    const int threads       = 256;                // 4 waves / block
    const int total_threads = total_waves * 64;
    const int blocks        = (total_threads + threads - 1) / threads;  // 32000

    dcn_kernel<<<blocks, threads, 0, stream>>>(x, offset, mask, out);
}

// Round 2
// 53.456 us; speedup vs baseline: 1.8353x; 1.8353x over previous
//
#include <hip/hip_runtime.h>

#define G_ 8
#define C_ 64
#define K_ 9
#define H_ 100
#define W_ 160

// One wave per pixel. Lane octet (8 lanes) per group; each lane owns 8 channels
// (two float4 halves: ch = li*4 .. li*4+3 and 32+li*4 .. 32+li*4+3).
__global__ __launch_bounds__(256) void dcn_kernel(
    const float* __restrict__ x,      // [H,W,G*C]
    const float* __restrict__ offset, // [H,W,G*K*2]
    const float* __restrict__ mask,   // [H,W,G*K]
    float* __restrict__ out)          // [H,W,G*C]
{
    const int pix = (int)((blockIdx.x * blockDim.x + threadIdx.x) >> 6);
    if (pix >= H_ * W_) return;
    const int lane = threadIdx.x & 63;
    const int g  = lane >> 3;   // group handled by this octet
    const int li = lane & 7;    // lane within octet -> channel slice
    const int w = pix % W_;
    const int h = pix / W_;

    const int pixg = pix * G_ + g;
    const float* mptr = mask   + (size_t)pixg * K_;
    const float* optr = offset + (size_t)pixg * (K_ * 2);

    // softmax over the 9 mask logits of this octet's group
    float mv[K_];
    float mmax = -1e30f;
#pragma unroll
    for (int k = 0; k < K_; ++k) { mv[k] = mptr[k]; mmax = fmaxf(mmax, mv[k]); }
    float msum = 0.f;
#pragma unroll
    for (int k = 0; k < K_; ++k) { mv[k] = __expf(mv[k] - mmax); msum += mv[k]; }
    const float minv = 1.f / msum;

    // lane's channel base within a pixel-row of x
    const float* xg = x + (size_t)g * C_ + li * 4;

    float a0 = 0.f, a1 = 0.f, a2 = 0.f, a3 = 0.f;
    float a4 = 0.f, a5 = 0.f, a6 = 0.f, a7 = 0.f;

#pragma unroll
    for (int k = 0; k < K_; ++k) {
        const float lh = (float)(h + k / 3 - 1) + optr[2 * k];
        const float lw = (float)(w + k % 3 - 1) + optr[2 * k + 1];
        const float fh0 = floorf(lh), fw0 = floorf(lw);
        const float th = lh - fh0, tw = lw - fw0;
        const int h0 = (int)fh0, w0 = (int)fw0;
        const float m = mv[k] * minv;

        // validity folded into weights; mask folded into h-weights
        const float wh0 = (h0 >= 0  && h0 < H_    ) ? (1.f - th) * m : 0.f;
        const float wh1 = (h0 >= -1 && h0 < H_ - 1) ? th * m         : 0.f;
        const float cw0 = (w0 >= 0  && w0 < W_    ) ? (1.f - tw)     : 0.f;
        const float cw1 = (w0 >= -1 && w0 < W_ - 1) ? tw             : 0.f;
        const float w00 = wh0 * cw0, w01 = wh0 * cw1;
        const float w10 = wh1 * cw0, w11 = wh1 * cw1;

        const int hc0 = min(max(h0,     0), H_ - 1);
        const int hc1 = min(max(h0 + 1, 0), H_ - 1);
        const int wc0 = min(max(w0,     0), W_ - 1);
        const int wc1 = min(max(w0 + 1, 0), W_ - 1);
        const int r0 = hc0 * W_, r1 = hc1 * W_;

        const float* p00 = xg + (size_t)(r0 + wc0) * (G_ * C_);
        const float* p01 = xg + (size_t)(r0 + wc1) * (G_ * C_);
        const float* p10 = xg + (size_t)(r1 + wc0) * (G_ * C_);
        const float* p11 = xg + (size_t)(r1 + wc1) * (G_ * C_);

#define ACC8(P, WT)                                                        \
        {                                                                  \
            const float4 lo = *(const float4*)(P);                         \
            const float4 hi = *(const float4*)((P) + 32);                  \
            a0 += lo.x * (WT); a1 += lo.y * (WT);                          \
            a2 += lo.z * (WT); a3 += lo.w * (WT);                          \
            a4 += hi.x * (WT); a5 += hi.y * (WT);                          \
            a6 += hi.z * (WT); a7 += hi.w * (WT);                          \
        }
        ACC8(p00, w00)
        ACC8(p01, w01)
        ACC8(p10, w10)
        ACC8(p11, w11)
#undef ACC8
    }

    float* op = out + (size_t)pixg * C_ + li * 4;
    *(float4*)op        = make_float4(a0, a1, a2, a3);
    *(float4*)(op + 32) = make_float4(a4, a5, a6, a7);
}

extern "C" void kernel_launch(void* const* d_in, const int* in_sizes, int n_in,
                              void* d_out, int out_size, void* d_ws, size_t ws_size,
                              hipStream_t stream) {
    const float* x      = (const float*)d_in[0];
    const float* offset = (const float*)d_in[1];
    const float* mask   = (const float*)d_in[2];
    float* out          = (float*)d_out;

    const int pixels        = H_ * W_;            // 16000 waves
    const int threads       = 256;                // 4 pixels / block
    const int total_threads = pixels * 64;
    const int blocks        = (total_threads + threads - 1) / threads;  // 4000

    dcn_kernel<<<blocks, threads, 0, stream>>>(x, offset, mask, out);
}

// Round 3
// 45.747 us; speedup vs baseline: 2.1446x; 1.1685x over previous
//
#include <hip/hip_runtime.h>

#define G_ 8
#define C_ 64
#define K_ 9
#define H_ 100
#define W_ 160
#define NX_ (H_ * W_ * G_ * C_)   // 5,120,000 x elements

// ---------- Pass 1: x f32 -> bf16 (RNE), into d_ws ----------
__device__ __forceinline__ unsigned bf16_rne(float f) {
    unsigned u = __float_as_uint(f);
    return (u + 0x7fffu + ((u >> 16) & 1u)) >> 16;
}

__global__ __launch_bounds__(256) void convert_kernel(
    const float* __restrict__ x, unsigned short* __restrict__ xb)
{
    const int i = (int)(blockIdx.x * blockDim.x + threadIdx.x) * 8;
    if (i >= NX_) return;
    const float4 a = *(const float4*)(x + i);
    const float4 b = *(const float4*)(x + i + 4);
    uint4 o;
    o.x = bf16_rne(a.x) | (bf16_rne(a.y) << 16);
    o.y = bf16_rne(a.z) | (bf16_rne(a.w) << 16);
    o.z = bf16_rne(b.x) | (bf16_rne(b.y) << 16);
    o.w = bf16_rne(b.z) | (bf16_rne(b.w) << 16);
    *(uint4*)(xb + i) = o;
}

// ---------- Pass 2: gather in bf16. One wave per pixel; lane-octet per group;
// each lane owns 8 contiguous channels (li*8 .. li*8+7). ----------
__global__ __launch_bounds__(256) void dcn_bf16_kernel(
    const unsigned short* __restrict__ xb, // [H,W,G*C] bf16
    const float* __restrict__ offset,      // [H,W,G*K*2]
    const float* __restrict__ mask,        // [H,W,G*K]
    float* __restrict__ out)               // [H,W,G*C]
{
    const int pix = (int)((blockIdx.x * blockDim.x + threadIdx.x) >> 6);
    if (pix >= H_ * W_) return;
    const int lane = threadIdx.x & 63;
    const int g  = lane >> 3;
    const int li = lane & 7;
    const int w = pix % W_;
    const int h = pix / W_;

    const int pixg = pix * G_ + g;
    const float* mptr = mask   + (size_t)pixg * K_;
    const float* optr = offset + (size_t)pixg * (K_ * 2);

    float mv[K_];
    float mmax = -1e30f;
#pragma unroll
    for (int k = 0; k < K_; ++k) { mv[k] = mptr[k]; mmax = fmaxf(mmax, mv[k]); }
    float msum = 0.f;
#pragma unroll
    for (int k = 0; k < K_; ++k) { mv[k] = __expf(mv[k] - mmax); msum += mv[k]; }
    const float minv = 1.f / msum;

    const unsigned short* xg = xb + (size_t)g * C_ + li * 8;

    float a0 = 0.f, a1 = 0.f, a2 = 0.f, a3 = 0.f;
    float a4 = 0.f, a5 = 0.f, a6 = 0.f, a7 = 0.f;

#pragma unroll
    for (int k = 0; k < K_; ++k) {
        const float lh = (float)(h + k / 3 - 1) + optr[2 * k];
        const float lw = (float)(w + k % 3 - 1) + optr[2 * k + 1];
        const float fh0 = floorf(lh), fw0 = floorf(lw);
        const float th = lh - fh0, tw = lw - fw0;
        const int h0 = (int)fh0, w0 = (int)fw0;
        const float m = mv[k] * minv;

        const float wh0 = (h0 >= 0  && h0 < H_    ) ? (1.f - th) * m : 0.f;
        const float wh1 = (h0 >= -1 && h0 < H_ - 1) ? th * m         : 0.f;
        const float cw0 = (w0 >= 0  && w0 < W_    ) ? (1.f - tw)     : 0.f;
        const float cw1 = (w0 >= -1 && w0 < W_ - 1) ? tw             : 0.f;
        const float w00 = wh0 * cw0, w01 = wh0 * cw1;
        const float w10 = wh1 * cw0, w11 = wh1 * cw1;

        const int hc0 = min(max(h0,     0), H_ - 1);
        const int hc1 = min(max(h0 + 1, 0), H_ - 1);
        const int wc0 = min(max(w0,     0), W_ - 1);
        const int wc1 = min(max(w0 + 1, 0), W_ - 1);
        const int r0 = hc0 * W_, r1 = hc1 * W_;

        const unsigned short* p00 = xg + (size_t)(r0 + wc0) * (G_ * C_);
        const unsigned short* p01 = xg + (size_t)(r0 + wc1) * (G_ * C_);
        const unsigned short* p10 = xg + (size_t)(r1 + wc0) * (G_ * C_);
        const unsigned short* p11 = xg + (size_t)(r1 + wc1) * (G_ * C_);

#define ACC8(P, WT)                                                         \
        {                                                                   \
            const uint4 q = *(const uint4*)(P);                             \
            a0 += __uint_as_float(q.x << 16)          * (WT);               \
            a1 += __uint_as_float(q.x & 0xffff0000u)  * (WT);               \
            a2 += __uint_as_float(q.y << 16)          * (WT);               \
            a3 += __uint_as_float(q.y & 0xffff0000u)  * (WT);               \
            a4 += __uint_as_float(q.z << 16)          * (WT);               \
            a5 += __uint_as_float(q.z & 0xffff0000u)  * (WT);               \
            a6 += __uint_as_float(q.w << 16)          * (WT);               \
            a7 += __uint_as_float(q.w & 0xffff0000u)  * (WT);               \
        }
        ACC8(p00, w00)
        ACC8(p01, w01)
        ACC8(p10, w10)
        ACC8(p11, w11)
#undef ACC8
    }

    float* op = out + (size_t)pixg * C_ + li * 8;
    *(float4*)op       = make_float4(a0, a1, a2, a3);
    *(float4*)(op + 4) = make_float4(a4, a5, a6, a7);
}

// ---------- Fallback: f32 gather (R2 kernel), used if ws too small ----------
__global__ __launch_bounds__(256) void dcn_f32_kernel(
    const float* __restrict__ x,
    const float* __restrict__ offset,
    const float* __restrict__ mask,
    float* __restrict__ out)
{
    const int pix = (int)((blockIdx.x * blockDim.x + threadIdx.x) >> 6);
    if (pix >= H_ * W_) return;
    const int lane = threadIdx.x & 63;
    const int g  = lane >> 3;
    const int li = lane & 7;
    const int w = pix % W_;
    const int h = pix / W_;

    const int pixg = pix * G_ + g;
    const float* mptr = mask   + (size_t)pixg * K_;
    const float* optr = offset + (size_t)pixg * (K_ * 2);

    float mv[K_];
    float mmax = -1e30f;
#pragma unroll
    for (int k = 0; k < K_; ++k) { mv[k] = mptr[k]; mmax = fmaxf(mmax, mv[k]); }
    float msum = 0.f;
#pragma unroll
    for (int k = 0; k < K_; ++k) { mv[k] = __expf(mv[k] - mmax); msum += mv[k]; }
    const float minv = 1.f / msum;

    const float* xg = x + (size_t)g * C_ + li * 4;

    float a0 = 0.f, a1 = 0.f, a2 = 0.f, a3 = 0.f;
    float a4 = 0.f, a5 = 0.f, a6 = 0.f, a7 = 0.f;

#pragma unroll
    for (int k = 0; k < K_; ++k) {
        const float lh = (float)(h + k / 3 - 1) + optr[2 * k];
        const float lw = (float)(w + k % 3 - 1) + optr[2 * k + 1];
        const float fh0 = floorf(lh), fw0 = floorf(lw);
        const float th = lh - fh0, tw = lw - fw0;
        const int h0 = (int)fh0, w0 = (int)fw0;
        const float m = mv[k] * minv;

        const float wh0 = (h0 >= 0  && h0 < H_    ) ? (1.f - th) * m : 0.f;
        const float wh1 = (h0 >= -1 && h0 < H_ - 1) ? th * m         : 0.f;
        const float cw0 = (w0 >= 0  && w0 < W_    ) ? (1.f - tw)     : 0.f;
        const float cw1 = (w0 >= -1 && w0 < W_ - 1) ? tw             : 0.f;
        const float w00 = wh0 * cw0, w01 = wh0 * cw1;
        const float w10 = wh1 * cw0, w11 = wh1 * cw1;

        const int hc0 = min(max(h0,     0), H_ - 1);
        const int hc1 = min(max(h0 + 1, 0), H_ - 1);
        const int wc0 = min(max(w0,     0), W_ - 1);
        const int wc1 = min(max(w0 + 1, 0), W_ - 1);
        const int r0 = hc0 * W_, r1 = hc1 * W_;

        const float* p00 = xg + (size_t)(r0 + wc0) * (G_ * C_);
        const float* p01 = xg + (size_t)(r0 + wc1) * (G_ * C_);
        const float* p10 = xg + (size_t)(r1 + wc0) * (G_ * C_);
        const float* p11 = xg + (size_t)(r1 + wc1) * (G_ * C_);

#define ACC8(P, WT)                                                        \
        {                                                                  \
            const float4 lo = *(const float4*)(P);                         \
            const float4 hi = *(const float4*)((P) + 32);                  \
            a0 += lo.x * (WT); a1 += lo.y * (WT);                          \
            a2 += lo.z * (WT); a3 += lo.w * (WT);                          \
            a4 += hi.x * (WT); a5 += hi.y * (WT);                          \
            a6 += hi.z * (WT); a7 += hi.w * (WT);                          \
        }
        ACC8(p00, w00)
        ACC8(p01, w01)
        ACC8(p10, w10)
        ACC8(p11, w11)
#undef ACC8
    }

    float* op = out + (size_t)pixg * C_ + li * 4;
    *(float4*)op        = make_float4(a0, a1, a2, a3);
    *(float4*)(op + 32) = make_float4(a4, a5, a6, a7);
}

extern "C" void kernel_launch(void* const* d_in, const int* in_sizes, int n_in,
                              void* d_out, int out_size, void* d_ws, size_t ws_size,
                              hipStream_t stream) {
    const float* x      = (const float*)d_in[0];
    const float* offset = (const float*)d_in[1];
    const float* mask   = (const float*)d_in[2];
    float* out          = (float*)d_out;

    const int pixels        = H_ * W_;
    const int threads       = 256;
    const int total_threads = pixels * 64;
    const int blocks        = (total_threads + threads - 1) / threads;

    const size_t need = (size_t)NX_ * sizeof(unsigned short);
    if (ws_size >= need) {
        unsigned short* xb = (unsigned short*)d_ws;
        const int cthreads = 256;
        const int celems   = NX_ / 8;                       // 640,000 lanes
        const int cblocks  = (celems + cthreads - 1) / cthreads;
        convert_kernel<<<cblocks, cthreads, 0, stream>>>(x, xb);
        dcn_bf16_kernel<<<blocks, threads, 0, stream>>>(xb, offset, mask, out);
    } else {
        dcn_f32_kernel<<<blocks, threads, 0, stream>>>(x, offset, mask, out);
    }
}

// Round 4
// 42.962 us; speedup vs baseline: 2.2837x; 1.0648x over previous
//
#include <hip/hip_runtime.h>
#include <hip/hip_fp16.h>

#define G_ 8
#define C_ 64
#define K_ 9
#define H_ 100
#define W_ 160
#define NX_ (H_ * W_ * G_ * C_)   // 5,120,000 x elements

// ---------- Pass 1: x f32 -> f16 (RNE), into d_ws ----------
__global__ __launch_bounds__(256) void convert_kernel(
    const float* __restrict__ x, __half* __restrict__ xh)
{
    const int i = (int)(blockIdx.x * blockDim.x + threadIdx.x) * 8;
    if (i >= NX_) return;
    const float4 a = *(const float4*)(x + i);
    const float4 b = *(const float4*)(x + i + 4);
    __half2 h0 = __floats2half2_rn(a.x, a.y);
    __half2 h1 = __floats2half2_rn(a.z, a.w);
    __half2 h2 = __floats2half2_rn(b.x, b.y);
    __half2 h3 = __floats2half2_rn(b.z, b.w);
    uint4 o;
    o.x = *(unsigned*)&h0;
    o.y = *(unsigned*)&h1;
    o.z = *(unsigned*)&h2;
    o.w = *(unsigned*)&h3;
    *(uint4*)(xh + i) = o;
}

// ---------- Pass 2: f16 gather, packed hfma2 accumulate.
// One wave per pixel; lane-octet per group; lane owns 8 channels (li*8..+7).
// XCD-swizzled block index: XCD k owns a contiguous pixel band (L2 banding).
__global__ __launch_bounds__(256) void dcn_f16_kernel(
    const __half* __restrict__ xh,    // [H,W,G*C] f16
    const float* __restrict__ offset, // [H,W,G*K*2]
    const float* __restrict__ mask,   // [H,W,G*K]
    float* __restrict__ out)          // [H,W,G*C]
{
    // bijective XCD swizzle: 4000 blocks = 8 * 500
    const int bid = (int)blockIdx.x;
    const int vb  = (bid & 7) * 500 + (bid >> 3);
    const int pix = vb * 4 + (int)(threadIdx.x >> 6);
    if (pix >= H_ * W_) return;
    const int lane = threadIdx.x & 63;
    const int g  = lane >> 3;
    const int li = lane & 7;
    const int w = pix % W_;
    const int h = pix / W_;

    const int pixg = pix * G_ + g;
    const float* mptr = mask   + (size_t)pixg * K_;
    const float* optr = offset + (size_t)pixg * (K_ * 2);

    // softmax over the 9 mask logits of this octet's group
    float mv[K_];
    float mmax = -1e30f;
#pragma unroll
    for (int k = 0; k < K_; ++k) { mv[k] = mptr[k]; mmax = fmaxf(mmax, mv[k]); }
    float msum = 0.f;
#pragma unroll
    for (int k = 0; k < K_; ++k) { mv[k] = __expf(mv[k] - mmax); msum += mv[k]; }
    const float minv = 1.f / msum;

    const __half* xg = xh + (size_t)g * C_ + li * 8;

    // 3 f16 accumulation groups (k 0-2, 3-5, 6-8) x 4 channel-pairs,
    // folded to f32 at the end (bounds f16 accumulation error).
    __half2 acc[3][4];
#pragma unroll
    for (int gr = 0; gr < 3; ++gr)
#pragma unroll
        for (int p = 0; p < 4; ++p)
            acc[gr][p] = __half2(__half(0.f), __half(0.f));

#pragma unroll
    for (int k = 0; k < K_; ++k) {
        const int gr = k / 3;  // compile-time under unroll
        const float lh = (float)(h + k / 3 - 1) + optr[2 * k];
        const float lw = (float)(w + k % 3 - 1) + optr[2 * k + 1];
        const float fh0 = floorf(lh), fw0 = floorf(lw);
        const float th = lh - fh0, tw = lw - fw0;
        const int h0 = (int)fh0, w0 = (int)fw0;
        const float m = mv[k] * minv;

        const float wh0 = (h0 >= 0  && h0 < H_    ) ? (1.f - th) * m : 0.f;
        const float wh1 = (h0 >= -1 && h0 < H_ - 1) ? th * m         : 0.f;
        const float cw0 = (w0 >= 0  && w0 < W_    ) ? (1.f - tw)     : 0.f;
        const float cw1 = (w0 >= -1 && w0 < W_ - 1) ? tw             : 0.f;
        const float w00 = wh0 * cw0, w01 = wh0 * cw1;
        const float w10 = wh1 * cw0, w11 = wh1 * cw1;

        const int hc0 = min(max(h0,     0), H_ - 1);
        const int hc1 = min(max(h0 + 1, 0), H_ - 1);
        const int wc0 = min(max(w0,     0), W_ - 1);
        const int wc1 = min(max(w0 + 1, 0), W_ - 1);
        const int r0 = hc0 * W_, r1 = hc1 * W_;

        const uint4 q00 = *(const uint4*)(xg + (size_t)(r0 + wc0) * (G_ * C_));
        const uint4 q01 = *(const uint4*)(xg + (size_t)(r0 + wc1) * (G_ * C_));
        const uint4 q10 = *(const uint4*)(xg + (size_t)(r1 + wc0) * (G_ * C_));
        const uint4 q11 = *(const uint4*)(xg + (size_t)(r1 + wc1) * (G_ * C_));

        const __half2 W00 = __float2half2_rn(w00);
        const __half2 W01 = __float2half2_rn(w01);
        const __half2 W10 = __float2half2_rn(w10);
        const __half2 W11 = __float2half2_rn(w11);

#pragma unroll
        for (int p = 0; p < 4; ++p) {
            const __half2 v00 = ((const __half2*)&q00)[p];
            const __half2 v01 = ((const __half2*)&q01)[p];
            const __half2 v10 = ((const __half2*)&q10)[p];
            const __half2 v11 = ((const __half2*)&q11)[p];
            __half2 a = acc[gr][p];
            a = __hfma2(v00, W00, a);
            a = __hfma2(v01, W01, a);
            a = __hfma2(v10, W10, a);
            a = __hfma2(v11, W11, a);
            acc[gr][p] = a;
        }
    }

    // fold the 3 f16 groups in f32 and store
    float2 s0, s1, s2, s3;
    {
        float2 t;
        s0 = __half22float2(acc[0][0]);
        t = __half22float2(acc[1][0]); s0.x += t.x; s0.y += t.y;
        t = __half22float2(acc[2][0]); s0.x += t.x; s0.y += t.y;
        s1 = __half22float2(acc[0][1]);
        t = __half22float2(acc[1][1]); s1.x += t.x; s1.y += t.y;
        t = __half22float2(acc[2][1]); s1.x += t.x; s1.y += t.y;
        s2 = __half22float2(acc[0][2]);
        t = __half22float2(acc[1][2]); s2.x += t.x; s2.y += t.y;
        t = __half22float2(acc[2][2]); s2.x += t.x; s2.y += t.y;
        s3 = __half22float2(acc[0][3]);
        t = __half22float2(acc[1][3]); s3.x += t.x; s3.y += t.y;
        t = __half22float2(acc[2][3]); s3.x += t.x; s3.y += t.y;
    }

    float* op = out + (size_t)pixg * C_ + li * 8;
    *(float4*)op       = make_float4(s0.x, s0.y, s1.x, s1.y);
    *(float4*)(op + 4) = make_float4(s2.x, s2.y, s3.x, s3.y);
}

// ---------- Fallback: f32 gather, used if ws too small ----------
__global__ __launch_bounds__(256) void dcn_f32_kernel(
    const float* __restrict__ x,
    const float* __restrict__ offset,
    const float* __restrict__ mask,
    float* __restrict__ out)
{
    const int pix = (int)((blockIdx.x * blockDim.x + threadIdx.x) >> 6);
    if (pix >= H_ * W_) return;
    const int lane = threadIdx.x & 63;
    const int g  = lane >> 3;
    const int li = lane & 7;
    const int w = pix % W_;
    const int h = pix / W_;

    const int pixg = pix * G_ + g;
    const float* mptr = mask   + (size_t)pixg * K_;
    const float* optr = offset + (size_t)pixg * (K_ * 2);

    float mv[K_];
    float mmax = -1e30f;
#pragma unroll
    for (int k = 0; k < K_; ++k) { mv[k] = mptr[k]; mmax = fmaxf(mmax, mv[k]); }
    float msum = 0.f;
#pragma unroll
    for (int k = 0; k < K_; ++k) { mv[k] = __expf(mv[k] - mmax); msum += mv[k]; }
    const float minv = 1.f / msum;

    const float* xg = x + (size_t)g * C_ + li * 4;

    float a0 = 0.f, a1 = 0.f, a2 = 0.f, a3 = 0.f;
    float a4 = 0.f, a5 = 0.f, a6 = 0.f, a7 = 0.f;

#pragma unroll
    for (int k = 0; k < K_; ++k) {
        const float lh = (float)(h + k / 3 - 1) + optr[2 * k];
        const float lw = (float)(w + k % 3 - 1) + optr[2 * k + 1];
        const float fh0 = floorf(lh), fw0 = floorf(lw);
        const float th = lh - fh0, tw = lw - fw0;
        const int h0 = (int)fh0, w0 = (int)fw0;
        const float m = mv[k] * minv;

        const float wh0 = (h0 >= 0  && h0 < H_    ) ? (1.f - th) * m : 0.f;
        const float wh1 = (h0 >= -1 && h0 < H_ - 1) ? th * m         : 0.f;
        const float cw0 = (w0 >= 0  && w0 < W_    ) ? (1.f - tw)     : 0.f;
        const float cw1 = (w0 >= -1 && w0 < W_ - 1) ? tw             : 0.f;
        const float w00 = wh0 * cw0, w01 = wh0 * cw1;
        const float w10 = wh1 * cw0, w11 = wh1 * cw1;

        const int hc0 = min(max(h0,     0), H_ - 1);
        const int hc1 = min(max(h0 + 1, 0), H_ - 1);
        const int wc0 = min(max(w0,     0), W_ - 1);
        const int wc1 = min(max(w0 + 1, 0), W_ - 1);
        const int r0 = hc0 * W_, r1 = hc1 * W_;

        const float* p00 = xg + (size_t)(r0 + wc0) * (G_ * C_);
        const float* p01 = xg + (size_t)(r0 + wc1) * (G_ * C_);
        const float* p10 = xg + (size_t)(r1 + wc0) * (G_ * C_);
        const float* p11 = xg + (size_t)(r1 + wc1) * (G_ * C_);

#define ACC8(P, WT)                                                        \
        {                                                                  \
            const float4 lo = *(const float4*)(P);                         \
            const float4 hi = *(const float4*)((P) + 32);                  \
            a0 += lo.x * (WT); a1 += lo.y * (WT);                          \
            a2 += lo.z * (WT); a3 += lo.w * (WT);                          \
            a4 += hi.x * (WT); a5 += hi.y * (WT);                          \
            a6 += hi.z * (WT); a7 += hi.w * (WT);                          \
        }
        ACC8(p00, w00)
        ACC8(p01, w01)
        ACC8(p10, w10)
        ACC8(p11, w11)
#undef ACC8
    }

    float* op = out + (size_t)pixg * C_ + li * 4;
    *(float4*)op        = make_float4(a0, a1, a2, a3);
    *(float4*)(op + 32) = make_float4(a4, a5, a6, a7);
}

extern "C" void kernel_launch(void* const* d_in, const int* in_sizes, int n_in,
                              void* d_out, int out_size, void* d_ws, size_t ws_size,
                              hipStream_t stream) {
    const float* x      = (const float*)d_in[0];
    const float* offset = (const float*)d_in[1];
    const float* mask   = (const float*)d_in[2];
    float* out          = (float*)d_out;

    const int pixels        = H_ * W_;
    const int threads       = 256;
    const int total_threads = pixels * 64;
    const int blocks        = (total_threads + threads - 1) / threads;  // 4000

    const size_t need = (size_t)NX_ * sizeof(__half);
    if (ws_size >= need) {
        __half* xh = (__half*)d_ws;
        const int cthreads = 256;
        const int celems   = NX_ / 8;
        const int cblocks  = (celems + cthreads - 1) / cthreads;
        convert_kernel<<<cblocks, cthreads, 0, stream>>>(x, xh);
        dcn_f16_kernel<<<blocks, threads, 0, stream>>>(xh, offset, mask, out);
    } else {
        dcn_f32_kernel<<<blocks, threads, 0, stream>>>(x, offset, mask, out);
    }
}

// Round 5
// 41.908 us; speedup vs baseline: 2.3410x; 1.0251x over previous
//
#include <hip/hip_runtime.h>
#include <hip/hip_fp16.h>

#define G_ 8
#define C_ 64
#define K_ 9
#define H_ 100
#define W_ 160
#define NX_ (H_ * W_ * G_ * C_)   // 5,120,000 x elements

// ---------- Pass 1: x f32 -> f16 (RNE), into d_ws ----------
__global__ __launch_bounds__(256) void convert_kernel(
    const float* __restrict__ x, __half* __restrict__ xh)
{
    const int i = (int)(blockIdx.x * blockDim.x + threadIdx.x) * 8;
    if (i >= NX_) return;
    const float4 a = *(const float4*)(x + i);
    const float4 b = *(const float4*)(x + i + 4);
    __half2 h0 = __floats2half2_rn(a.x, a.y);
    __half2 h1 = __floats2half2_rn(a.z, a.w);
    __half2 h2 = __floats2half2_rn(b.x, b.y);
    __half2 h3 = __floats2half2_rn(b.z, b.w);
    uint4 o;
    o.x = *(unsigned*)&h0;
    o.y = *(unsigned*)&h1;
    o.z = *(unsigned*)&h2;
    o.w = *(unsigned*)&h3;
    *(uint4*)(xh + i) = o;
}

// ---------- Pass 2: f16 gather, packed hfma2 accumulate.
// 1024-thread blocks (16 waves arrive as one cohort -> fills the CU).
// One wave per pixel; lane-octet per group; lane owns 8 channels (li*8..+7).
// XCD banding: 1000 blocks = 8 XCD * 125; band = 2000 contiguous pixels.
__global__ __launch_bounds__(1024) void dcn_f16_kernel(
    const __half* __restrict__ xh,    // [H,W,G*C] f16
    const float* __restrict__ offset, // [H,W,G*K*2]
    const float* __restrict__ mask,   // [H,W,G*K]
    float* __restrict__ out)          // [H,W,G*C]
{
    // bijective XCD swizzle: 1000 blocks = 8 * 125
    const int bid = (int)blockIdx.x;
    const int vb  = (bid & 7) * 125 + (bid >> 3);
    const int pix = vb * 16 + (int)(threadIdx.x >> 6);
    if (pix >= H_ * W_) return;
    const int lane = threadIdx.x & 63;
    const int g  = lane >> 3;
    const int li = lane & 7;
    const int w = pix % W_;
    const int h = pix / W_;

    const int pixg = pix * G_ + g;
    const float* mptr = mask   + (size_t)pixg * K_;
    const float* optr = offset + (size_t)pixg * (K_ * 2);

    // softmax over the 9 mask logits of this octet's group
    float mv[K_];
    float mmax = -1e30f;
#pragma unroll
    for (int k = 0; k < K_; ++k) { mv[k] = mptr[k]; mmax = fmaxf(mmax, mv[k]); }
    float msum = 0.f;
#pragma unroll
    for (int k = 0; k < K_; ++k) { mv[k] = __expf(mv[k] - mmax); msum += mv[k]; }
    const float minv = 1.f / msum;

    const __half* xg = xh + (size_t)g * C_ + li * 8;

    // 3 f16 accumulation groups (k 0-2, 3-5, 6-8) x 4 channel-pairs,
    // folded to f32 at the end (bounds f16 accumulation error).
    __half2 acc[3][4];
#pragma unroll
    for (int gr = 0; gr < 3; ++gr)
#pragma unroll
        for (int p = 0; p < 4; ++p)
            acc[gr][p] = __half2(__half(0.f), __half(0.f));

#pragma unroll
    for (int k = 0; k < K_; ++k) {
        const int gr = k / 3;  // compile-time under unroll
        const float lh = (float)(h + k / 3 - 1) + optr[2 * k];
        const float lw = (float)(w + k % 3 - 1) + optr[2 * k + 1];
        const float fh0 = floorf(lh), fw0 = floorf(lw);
        const float th = lh - fh0, tw = lw - fw0;
        const int h0 = (int)fh0, w0 = (int)fw0;
        const float m = mv[k] * minv;

        const float wh0 = (h0 >= 0  && h0 < H_    ) ? (1.f - th) * m : 0.f;
        const float wh1 = (h0 >= -1 && h0 < H_ - 1) ? th * m         : 0.f;
        const float cw0 = (w0 >= 0  && w0 < W_    ) ? (1.f - tw)     : 0.f;
        const float cw1 = (w0 >= -1 && w0 < W_ - 1) ? tw             : 0.f;
        const float w00 = wh0 * cw0, w01 = wh0 * cw1;
        const float w10 = wh1 * cw0, w11 = wh1 * cw1;

        const int hc0 = min(max(h0,     0), H_ - 1);
        const int hc1 = min(max(h0 + 1, 0), H_ - 1);
        const int wc0 = min(max(w0,     0), W_ - 1);
        const int wc1 = min(max(w0 + 1, 0), W_ - 1);
        const int r0 = hc0 * W_, r1 = hc1 * W_;

        const uint4 q00 = *(const uint4*)(xg + (size_t)(r0 + wc0) * (G_ * C_));
        const uint4 q01 = *(const uint4*)(xg + (size_t)(r0 + wc1) * (G_ * C_));
        const uint4 q10 = *(const uint4*)(xg + (size_t)(r1 + wc0) * (G_ * C_));
        const uint4 q11 = *(const uint4*)(xg + (size_t)(r1 + wc1) * (G_ * C_));

        const __half2 W00 = __float2half2_rn(w00);
        const __half2 W01 = __float2half2_rn(w01);
        const __half2 W10 = __float2half2_rn(w10);
        const __half2 W11 = __float2half2_rn(w11);

#pragma unroll
        for (int p = 0; p < 4; ++p) {
            const __half2 v00 = ((const __half2*)&q00)[p];
            const __half2 v01 = ((const __half2*)&q01)[p];
            const __half2 v10 = ((const __half2*)&q10)[p];
            const __half2 v11 = ((const __half2*)&q11)[p];
            __half2 a = acc[gr][p];
            a = __hfma2(v00, W00, a);
            a = __hfma2(v01, W01, a);
            a = __hfma2(v10, W10, a);
            a = __hfma2(v11, W11, a);
            acc[gr][p] = a;
        }
    }

    // fold the 3 f16 groups in f32 and store
    float2 s0, s1, s2, s3;
    {
        float2 t;
        s0 = __half22float2(acc[0][0]);
        t = __half22float2(acc[1][0]); s0.x += t.x; s0.y += t.y;
        t = __half22float2(acc[2][0]); s0.x += t.x; s0.y += t.y;
        s1 = __half22float2(acc[0][1]);
        t = __half22float2(acc[1][1]); s1.x += t.x; s1.y += t.y;
        t = __half22float2(acc[2][1]); s1.x += t.x; s1.y += t.y;
        s2 = __half22float2(acc[0][2]);
        t = __half22float2(acc[1][2]); s2.x += t.x; s2.y += t.y;
        t = __half22float2(acc[2][2]); s2.x += t.x; s2.y += t.y;
        s3 = __half22float2(acc[0][3]);
        t = __half22float2(acc[1][3]); s3.x += t.x; s3.y += t.y;
        t = __half22float2(acc[2][3]); s3.x += t.x; s3.y += t.y;
    }

    float* op = out + (size_t)pixg * C_ + li * 8;
    *(float4*)op       = make_float4(s0.x, s0.y, s1.x, s1.y);
    *(float4*)(op + 4) = make_float4(s2.x, s2.y, s3.x, s3.y);
}

// ---------- Fallback: f32 gather, used if ws too small ----------
__global__ __launch_bounds__(256) void dcn_f32_kernel(
    const float* __restrict__ x,
    const float* __restrict__ offset,
    const float* __restrict__ mask,
    float* __restrict__ out)
{
    const int pix = (int)((blockIdx.x * blockDim.x + threadIdx.x) >> 6);
    if (pix >= H_ * W_) return;
    const int lane = threadIdx.x & 63;
    const int g  = lane >> 3;
    const int li = lane & 7;
    const int w = pix % W_;
    const int h = pix / W_;

    const int pixg = pix * G_ + g;
    const float* mptr = mask   + (size_t)pixg * K_;
    const float* optr = offset + (size_t)pixg * (K_ * 2);

    float mv[K_];
    float mmax = -1e30f;
#pragma unroll
    for (int k = 0; k < K_; ++k) { mv[k] = mptr[k]; mmax = fmaxf(mmax, mv[k]); }
    float msum = 0.f;
#pragma unroll
    for (int k = 0; k < K_; ++k) { mv[k] = __expf(mv[k] - mmax); msum += mv[k]; }
    const float minv = 1.f / msum;

    const float* xg = x + (size_t)g * C_ + li * 4;

    float a0 = 0.f, a1 = 0.f, a2 = 0.f, a3 = 0.f;
    float a4 = 0.f, a5 = 0.f, a6 = 0.f, a7 = 0.f;

#pragma unroll
    for (int k = 0; k < K_; ++k) {
        const float lh = (float)(h + k / 3 - 1) + optr[2 * k];
        const float lw = (float)(w + k % 3 - 1) + optr[2 * k + 1];
        const float fh0 = floorf(lh), fw0 = floorf(lw);
        const float th = lh - fh0, tw = lw - fw0;
        const int h0 = (int)fh0, w0 = (int)fw0;
        const float m = mv[k] * minv;

        const float wh0 = (h0 >= 0  && h0 < H_    ) ? (1.f - th) * m : 0.f;
        const float wh1 = (h0 >= -1 && h0 < H_ - 1) ? th * m         : 0.f;
        const float cw0 = (w0 >= 0  && w0 < W_    ) ? (1.f - tw)     : 0.f;
        const float cw1 = (w0 >= -1 && w0 < W_ - 1) ? tw             : 0.f;
        const float w00 = wh0 * cw0, w01 = wh0 * cw1;
        const float w10 = wh1 * cw0, w11 = wh1 * cw1;

        const int hc0 = min(max(h0,     0), H_ - 1);
        const int hc1 = min(max(h0 + 1, 0), H_ - 1);
        const int wc0 = min(max(w0,     0), W_ - 1);
        const int wc1 = min(max(w0 + 1, 0), W_ - 1);
        const int r0 = hc0 * W_, r1 = hc1 * W_;

        const float* p00 = xg + (size_t)(r0 + wc0) * (G_ * C_);
        const float* p01 = xg + (size_t)(r0 + wc1) * (G_ * C_);
        const float* p10 = xg + (size_t)(r1 + wc0) * (G_ * C_);
        const float* p11 = xg + (size_t)(r1 + wc1) * (G_ * C_);

#define ACC8(P, WT)                                                        \
        {                                                                  \
            const float4 lo = *(const float4*)(P);                         \
            const float4 hi = *(const float4*)((P) + 32);                  \
            a0 += lo.x * (WT); a1 += lo.y * (WT);                          \
            a2 += lo.z * (WT); a3 += lo.w * (WT);                          \
            a4 += hi.x * (WT); a5 += hi.y * (WT);                          \
            a6 += hi.z * (WT); a7 += hi.w * (WT);                          \
        }
        ACC8(p00, w00)
        ACC8(p01, w01)
        ACC8(p10, w10)
        ACC8(p11, w11)
#undef ACC8
    }

    float* op = out + (size_t)pixg * C_ + li * 4;
    *(float4*)op        = make_float4(a0, a1, a2, a3);
    *(float4*)(op + 32) = make_float4(a4, a5, a6, a7);
}

extern "C" void kernel_launch(void* const* d_in, const int* in_sizes, int n_in,
                              void* d_out, int out_size, void* d_ws, size_t ws_size,
                              hipStream_t stream) {
    const float* x      = (const float*)d_in[0];
    const float* offset = (const float*)d_in[1];
    const float* mask   = (const float*)d_in[2];
    float* out          = (float*)d_out;

    const size_t need = (size_t)NX_ * sizeof(__half);
    if (ws_size >= need) {
        __half* xh = (__half*)d_ws;
        const int cthreads = 256;
        const int celems   = NX_ / 8;
        const int cblocks  = (celems + cthreads - 1) / cthreads;
        convert_kernel<<<cblocks, cthreads, 0, stream>>>(x, xh);

        const int threads = 1024;                 // 16 waves / block
        const int blocks  = (H_ * W_) / 16;       // 1000
        dcn_f16_kernel<<<blocks, threads, 0, stream>>>(xh, offset, mask, out);
    } else {
        const int pixels        = H_ * W_;
        const int threads       = 256;
        const int total_threads = pixels * 64;
        const int blocks        = (total_threads + threads - 1) / threads;
        dcn_f32_kernel<<<blocks, threads, 0, stream>>>(x, offset, mask, out);
    }
}